// Round 8
// baseline (199.104 us; speedup 1.0000x reference)
//
#include <hip/hip_runtime.h>
#include <cstdint>

#define T_  2048
#define D_  64
#define BH_ 32
#define W_  256

typedef float f32x4 __attribute__((ext_vector_type(4)));
using bf16x8 = __attribute__((ext_vector_type(8))) short;   // 8 bf16 in 4 VGPRs

__device__ inline unsigned short f2bf(float x) {            // RNE fp32->bf16
  unsigned u = __float_as_uint(x);
  u = (u + 0x7fffu + ((u >> 16) & 1u)) >> 16;
  return (unsigned short)u;
}

// K1: per (bh, 128-row tile): (a) convert pop rows to bf16, (b) sliding-window
// scan -> gene fitness with analytic rowsum normalization folded in -> bf16.
__global__ __launch_bounds__(256) void k1_prep(const float* __restrict__ pop,
                                               unsigned short* __restrict__ pop16,
                                               unsigned short* __restrict__ gfs16) {
  const int unit = blockIdx.x;            // 0..511
  const int i0   = (unit & 15) * 128;
  const int bh   = unit >> 4;
  const int tid  = threadIdx.x;
  const float* Pb = pop + (size_t)bh * T_ * D_;

  // ---- pop -> bf16 (rows i0..i0+127, each row exactly once across grid) ----
  {
    unsigned short* Qb = pop16 + (size_t)bh * T_ * D_;
    for (int e = tid; e < 128 * D_ / 4; e += 256) {
      const int row = e >> 4, d4 = e & 15;
      const f32x4 v = *reinterpret_cast<const f32x4*>(&Pb[(size_t)(i0 + row) * D_ + d4 * 4]);
      uint2 pk;
      pk.x = (unsigned)f2bf(v.x) | ((unsigned)f2bf(v.y) << 16);
      pk.y = (unsigned)f2bf(v.z) | ((unsigned)f2bf(v.w) << 16);
      *reinterpret_cast<uint2*>(&Qb[(size_t)(i0 + row) * D_ + d4 * 4]) = pk;
    }
  }

  // ---- gene fitness rows i0..i0+127 -> gfs16 (rowsum folded, closed form) ----
  const int w = tid >> 6;                 // 4 waves x 32 rows
  const int d = tid & 63;                 // lane == feature dim
  const int ib = i0 + w * 32;
  const float* P = Pb + d;
  unsigned short* G = gfs16 + (size_t)bh * T_ * D_ + d;

  int s0 = ib - (W_ - 1); if (s0 < 0) s0 = 0;
  const int jend = ib + 1;
  float p0=0.f,p1=0.f,p2=0.f,p3=0.f,p4=0.f,p5=0.f,p6=0.f,p7=0.f;
  int j = s0;
  for (; j + 8 <= jend; j += 8) {
    p0 += P[(size_t)(j+0)*D_]; p1 += P[(size_t)(j+1)*D_];
    p2 += P[(size_t)(j+2)*D_]; p3 += P[(size_t)(j+3)*D_];
    p4 += P[(size_t)(j+4)*D_]; p5 += P[(size_t)(j+5)*D_];
    p6 += P[(size_t)(j+6)*D_]; p7 += P[(size_t)(j+7)*D_];
  }
  for (; j < jend; ++j) p0 += P[(size_t)j*D_];
  float isum = ((p0+p1)+(p2+p3)) + ((p4+p5)+(p6+p7));

  for (int r = 0; r < 32; ++r) {
    const int i = ib + r;
    if (r > 0) {
      isum += P[(size_t)i * D_];
      const int jd = i - W_;
      if (jd >= 0) isum -= P[(size_t)jd * D_];
    }
    const float cnt   = (i + 1 < W_) ? (float)(i + 1) : (float)W_;
    const float denom = isum / cnt + 0.5f;
    const float rinv  = 1.0f / denom;
    float s = rinv;
    #pragma unroll
    for (int m = 32; m >= 1; m >>= 1) s += __shfl_xor(s, m);
    float rowsum = cnt * (64.0f / s - 0.5f);
    rowsum = fmaxf(rowsum, 1e-10f);
    G[(size_t)i * D_] = f2bf(rinv / (rowsum * s));
  }
}

// K2: one block per 128-row strip; writes the ENTIRE strip (all 2048 cols of
// each row): band values via swapped-operand MFMA, zeros elsewhere. Swapped
// operands mfma(A=pop(j), B=gfs(i)) give D[j][i]=O[i][j] with lane l&15 = out
// ROW i and regs = 4 consecutive out COLS j -> masked f32x4 NT stores.
__global__ __launch_bounds__(256) void k2_strip(const unsigned short* __restrict__ pop16,
                                                const unsigned short* __restrict__ gfs16,
                                                float* __restrict__ out) {
  const int unit = blockIdx.x;            // 0..511
  const int i0   = (unit & 15) * 128;
  const int bh   = unit >> 4;
  const int tid  = threadIdx.x;
  const int lane = tid & 63, wv = tid >> 6;
  const int l15 = lane & 15, l4 = lane >> 4;
  float* Ob = out + (size_t)bh * T_ * T_;
  const unsigned short* Gb = gfs16 + (size_t)bh * T_ * D_;
  const unsigned short* Qb = pop16 + (size_t)bh * T_ * D_;
  const int ib0 = i0 + wv * 32;           // wave's 32 rows

  // B-operand fragments (gfs, i-index): 2 i-tiles x 2 k-halves
  const bf16x8 g00 = *reinterpret_cast<const bf16x8*>(&Gb[(size_t)(ib0      + l15) * D_      + l4 * 8]);
  const bf16x8 g01 = *reinterpret_cast<const bf16x8*>(&Gb[(size_t)(ib0      + l15) * D_ + 32 + l4 * 8]);
  const bf16x8 g10 = *reinterpret_cast<const bf16x8*>(&Gb[(size_t)(ib0 + 16 + l15) * D_      + l4 * 8]);
  const bf16x8 g11 = *reinterpret_cast<const bf16x8*>(&Gb[(size_t)(ib0 + 16 + l15) * D_ + 32 + l4 * 8]);

  // ---- band region: j-tiles jb = i0-256 + jt*16 ----
  for (int jt = 0; jt < 24; ++jt) {
    const int jb = i0 - 256 + jt * 16;
    if (jb < 0) continue;                 // uniform across block
    const bf16x8 p0 = *reinterpret_cast<const bf16x8*>(&Qb[(size_t)(jb + l15) * D_      + l4 * 8]);
    const bf16x8 p1 = *reinterpret_cast<const bf16x8*>(&Qb[(size_t)(jb + l15) * D_ + 32 + l4 * 8]);
    f32x4 c0 = {0.f, 0.f, 0.f, 0.f};
    f32x4 c1 = {0.f, 0.f, 0.f, 0.f};
    c0 = __builtin_amdgcn_mfma_f32_16x16x32_bf16(p0, g00, c0, 0, 0, 0);
    c0 = __builtin_amdgcn_mfma_f32_16x16x32_bf16(p1, g01, c0, 0, 0, 0);
    c1 = __builtin_amdgcn_mfma_f32_16x16x32_bf16(p0, g10, c1, 0, 0, 0);
    c1 = __builtin_amdgcn_mfma_f32_16x16x32_bf16(p1, g11, c1, 0, 0, 0);

    const int jq = jb + l4 * 4;           // 4 consecutive cols per lane
    {
      const int i = ib0 + l15;
      f32x4 v;
      #pragma unroll
      for (int r = 0; r < 4; ++r)
        v[r] = ((unsigned)(i - (jq + r)) < 256u) ? c0[r] : 0.f;
      __builtin_nontemporal_store(v, reinterpret_cast<f32x4*>(&Ob[(size_t)i * T_ + jq]));
    }
    {
      const int i = ib0 + 16 + l15;
      f32x4 v;
      #pragma unroll
      for (int r = 0; r < 4; ++r)
        v[r] = ((unsigned)(i - (jq + r)) < 256u) ? c1[r] : 0.f;
      __builtin_nontemporal_store(v, reinterpret_cast<f32x4*>(&Ob[(size_t)i * T_ + jq]));
    }
  }

  // ---- zero segments outside [Lz, R) for the wave's 32 rows ----
  int Lz = i0 - 256; if (Lz < 0) Lz = 0;
  const int L4n = Lz >> 2;
  const int R   = i0 + 128;
  const int W4r = (T_ - R) >> 2;
  const f32x4 z4 = {0.f, 0.f, 0.f, 0.f};
  for (int r = 0; r < 32; ++r) {
    float* orow = Ob + (size_t)(ib0 + r) * T_;
    f32x4* oL = reinterpret_cast<f32x4*>(orow);
    for (int c = lane; c < L4n; c += 64)
      __builtin_nontemporal_store(z4, &oL[c]);
    f32x4* oR = reinterpret_cast<f32x4*>(orow + R);
    for (int c = lane; c < W4r; c += 64)
      __builtin_nontemporal_store(z4, &oR[c]);
  }
}

extern "C" void kernel_launch(void* const* d_in, const int* in_sizes, int n_in,
                              void* d_out, int out_size, void* d_ws, size_t ws_size,
                              hipStream_t stream) {
  const float* pop = (const float*)d_in[0];
  float* out = (float*)d_out;
  unsigned short* pop16 = (unsigned short*)d_ws;                        // 8.39 MB
  unsigned short* gfs16 = (unsigned short*)((char*)d_ws + (size_t)BH_ * T_ * D_ * 2);

  dim3 blk(256);
  hipLaunchKernelGGL(k1_prep,  dim3(16 * BH_), blk, 0, stream, pop, pop16, gfs16);
  hipLaunchKernelGGL(k2_strip, dim3(16 * BH_), blk, 0, stream, pop16, gfs16, out);
}

// Round 9
// 155.611 us; speedup vs baseline: 1.2795x; 1.2795x over previous
//
#include <hip/hip_runtime.h>
#include <cstdint>

#define T_  2048
#define D_  64
#define BH_ 32
#define W_  256
#define GP  72   // LDS row pitch in shorts (144 B): fragment ds_read_b128 -> 2-way bank alias (free)

typedef float f32x4 __attribute__((ext_vector_type(4)));
using bf16x8 = __attribute__((ext_vector_type(8))) short;   // 8 bf16 in 4 VGPRs

__device__ inline unsigned short f2bf(float x) {            // RNE fp32->bf16
  unsigned u = __float_as_uint(x);
  u = (u + 0x7fffu + ((u >> 16) & 1u)) >> 16;
  return (unsigned short)u;
}

__device__ inline bf16x8 cvt8(const f32x4 lo, const f32x4 hi) {
  bf16x8 r;
  r[0] = (short)f2bf(lo.x); r[1] = (short)f2bf(lo.y);
  r[2] = (short)f2bf(lo.z); r[3] = (short)f2bf(lo.w);
  r[4] = (short)f2bf(hi.x); r[5] = (short)f2bf(hi.y);
  r[6] = (short)f2bf(hi.z); r[7] = (short)f2bf(hi.w);
  return r;
}

// One block per (bh, 128-row strip). Phases:
//  0) zero-fill the out-of-band segments of the strip (NT, full lines, no deps
//     -> these 437MB/global of writes start immediately and overlap A/B).
//  A) sliding-window scan -> gene fitness (analytic rowsum folded) -> bf16 LDS.
//  B) banded GEMM via swapped-operand mfma_16x16x32_bf16; pop fragments loaded
//     fp32 from global (L2/L3-resident) + converted in-reg; band stores are
//     REGULAR f32x4 (L2 merges the 64B row-segments into full lines).
__global__ __launch_bounds__(256) void fused_strip(const float* __restrict__ pop,
                                                   float* __restrict__ out) {
  __shared__ unsigned short Gs[128 * GP];
  const int unit = blockIdx.x;            // 0..511
  const int i0   = (unit & 15) * 128;
  const int bh   = unit >> 4;
  const int tid  = threadIdx.x;
  const int lane = tid & 63, wv = tid >> 6;
  const int l15 = lane & 15, l4 = lane >> 4;
  const float* Pb = pop + (size_t)bh * T_ * D_;
  float*       Ob = out + (size_t)bh * T_ * T_;
  const int ib0 = i0 + wv * 32;           // wave's 32 rows

  // ---- Phase 0: zero segments outside [max(i0-256,0), i0+128) ----
  {
    int Lz = i0 - 256; if (Lz < 0) Lz = 0;
    const int L4n = Lz >> 2;
    const int R   = i0 + 128;
    const int W4r = (T_ - R) >> 2;
    const f32x4 z4 = {0.f, 0.f, 0.f, 0.f};
    for (int r = 0; r < 32; ++r) {
      float* orow = Ob + (size_t)(ib0 + r) * T_;
      f32x4* oL = reinterpret_cast<f32x4*>(orow);
      for (int c = lane; c < L4n; c += 64)
        __builtin_nontemporal_store(z4, &oL[c]);
      f32x4* oR = reinterpret_cast<f32x4*>(orow + R);
      for (int c = lane; c < W4r; c += 64)
        __builtin_nontemporal_store(z4, &oR[c]);
    }
  }

  // ---- Phase A: scan rows ib0..ib0+31 -> Gs[row_local][d] (bf16) ----
  {
    const int d = lane;                   // lane == feature dim
    const float* P = Pb + d;
    int s0 = ib0 - (W_ - 1); if (s0 < 0) s0 = 0;
    const int jend = ib0 + 1;
    float p0=0.f,p1=0.f,p2=0.f,p3=0.f,p4=0.f,p5=0.f,p6=0.f,p7=0.f;
    int j = s0;
    for (; j + 8 <= jend; j += 8) {
      p0 += P[(size_t)(j+0)*D_]; p1 += P[(size_t)(j+1)*D_];
      p2 += P[(size_t)(j+2)*D_]; p3 += P[(size_t)(j+3)*D_];
      p4 += P[(size_t)(j+4)*D_]; p5 += P[(size_t)(j+5)*D_];
      p6 += P[(size_t)(j+6)*D_]; p7 += P[(size_t)(j+7)*D_];
    }
    for (; j < jend; ++j) p0 += P[(size_t)j*D_];
    float isum = ((p0+p1)+(p2+p3)) + ((p4+p5)+(p6+p7));

    for (int r = 0; r < 32; ++r) {
      const int i = ib0 + r;
      if (r > 0) {
        isum += P[(size_t)i * D_];
        const int jd = i - W_;
        if (jd >= 0) isum -= P[(size_t)jd * D_];
      }
      const float cnt   = (i + 1 < W_) ? (float)(i + 1) : (float)W_;
      const float denom = isum / cnt + 0.5f;
      const float rinv  = 1.0f / denom;
      float s = rinv;
      #pragma unroll
      for (int m = 32; m >= 1; m >>= 1) s += __shfl_xor(s, m);
      float rowsum = cnt * (64.0f / s - 0.5f);
      rowsum = fmaxf(rowsum, 1e-10f);
      Gs[(wv * 32 + r) * GP + d] = f2bf(rinv / (rowsum * s));
    }
  }
  __syncthreads();

  // ---- Phase B: band MFMA ----
  // gfs fragments from LDS (B-operand; lane l15 = i-row, l4*8 = k-offset)
  const bf16x8 g00 = *reinterpret_cast<const bf16x8*>(&Gs[(wv*32      + l15) * GP      + l4*8]);
  const bf16x8 g01 = *reinterpret_cast<const bf16x8*>(&Gs[(wv*32      + l15) * GP + 32 + l4*8]);
  const bf16x8 g10 = *reinterpret_cast<const bf16x8*>(&Gs[(wv*32 + 16 + l15) * GP      + l4*8]);
  const bf16x8 g11 = *reinterpret_cast<const bf16x8*>(&Gs[(wv*32 + 16 + l15) * GP + 32 + l4*8]);

  for (int jt = 0; jt < 24; ++jt) {
    const int jb = i0 - 256 + jt * 16;
    if (jb < 0) continue;                 // uniform across block
    const float* prow = &Pb[(size_t)(jb + l15) * D_];
    const f32x4 q0 = *reinterpret_cast<const f32x4*>(prow + l4*8);
    const f32x4 q1 = *reinterpret_cast<const f32x4*>(prow + l4*8 + 4);
    const f32x4 q2 = *reinterpret_cast<const f32x4*>(prow + 32 + l4*8);
    const f32x4 q3 = *reinterpret_cast<const f32x4*>(prow + 32 + l4*8 + 4);
    const bf16x8 p0 = cvt8(q0, q1);       // k = l4*8 .. +7
    const bf16x8 p1 = cvt8(q2, q3);       // k = 32 + l4*8 .. +7

    f32x4 c0 = {0.f, 0.f, 0.f, 0.f};
    f32x4 c1 = {0.f, 0.f, 0.f, 0.f};
    c0 = __builtin_amdgcn_mfma_f32_16x16x32_bf16(p0, g00, c0, 0, 0, 0);
    c0 = __builtin_amdgcn_mfma_f32_16x16x32_bf16(p1, g01, c0, 0, 0, 0);
    c1 = __builtin_amdgcn_mfma_f32_16x16x32_bf16(p0, g10, c1, 0, 0, 0);
    c1 = __builtin_amdgcn_mfma_f32_16x16x32_bf16(p1, g11, c1, 0, 0, 0);

    const int jq = jb + l4 * 4;           // 4 consecutive out-cols per lane
    {
      const int i = ib0 + l15;
      f32x4 v;
      #pragma unroll
      for (int r = 0; r < 4; ++r)
        v[r] = ((unsigned)(i - (jq + r)) < 256u) ? c0[r] : 0.f;
      *reinterpret_cast<f32x4*>(&Ob[(size_t)i * T_ + jq]) = v;   // regular store: L2 merges
    }
    {
      const int i = ib0 + 16 + l15;
      f32x4 v;
      #pragma unroll
      for (int r = 0; r < 4; ++r)
        v[r] = ((unsigned)(i - (jq + r)) < 256u) ? c1[r] : 0.f;
      *reinterpret_cast<f32x4*>(&Ob[(size_t)i * T_ + jq]) = v;
    }
  }
}

extern "C" void kernel_launch(void* const* d_in, const int* in_sizes, int n_in,
                              void* d_out, int out_size, void* d_ws, size_t ws_size,
                              hipStream_t stream) {
  const float* pop = (const float*)d_in[0];
  float* out = (float*)d_out;
  dim3 blk(256);
  hipLaunchKernelGGL(fused_strip, dim3(16 * BH_), blk, 0, stream, pop, out);
}

// Round 10
// 132.544 us; speedup vs baseline: 1.5022x; 1.1740x over previous
//
#include <hip/hip_runtime.h>
#include <cstdint>

#define T_  2048
#define D_  64
#define BH_ 32
#define W_  256
#define GP  72   // LDS row pitch in shorts (144 B)

typedef float f32x4 __attribute__((ext_vector_type(4)));
using bf16x8 = __attribute__((ext_vector_type(8))) short;   // 8 bf16 in 4 VGPRs

__device__ inline unsigned short f2bf(float x) {            // RNE fp32->bf16
  unsigned u = __float_as_uint(x);
  u = (u + 0x7fffu + ((u >> 16) & 1u)) >> 16;
  return (unsigned short)u;
}

__device__ inline bf16x8 cvt8(const f32x4 lo, const f32x4 hi) {
  bf16x8 r;
  r[0] = (short)f2bf(lo.x); r[1] = (short)f2bf(lo.y);
  r[2] = (short)f2bf(lo.z); r[3] = (short)f2bf(lo.w);
  r[4] = (short)f2bf(hi.x); r[5] = (short)f2bf(hi.y);
  r[6] = (short)f2bf(hi.z); r[7] = (short)f2bf(hi.w);
  return r;
}

// One block per (bh, 128-row strip). Phase order = loads first, bulk stores
// last (vmcnt completes in issue order; stores issued before loads would gate
// the loads' waitcnt on HBM store drain):
//  A) sliding-window scan -> gene fitness (analytic rowsum folded) -> bf16 LDS.
//     De-serialized: preloaded arrive/depart regs; 32-add prefix is the only
//     serial chain; 32 lane-reductions pipeline; divisions independent per row.
//  B) banded GEMM via swapped-operand mfma_16x16x32_bf16 (regular f32x4 stores,
//     L2 merges 64B row segments).
//  0) zero-fill of out-of-band segments (NT full-line streams, fire-and-forget;
//     drain overlaps other blocks' phases and the kernel tail).
__global__ __launch_bounds__(256, 2) void fused_strip(const float* __restrict__ pop,
                                                      float* __restrict__ out) {
  __shared__ unsigned short Gs[128 * GP];
  const int unit = blockIdx.x;            // 0..511
  const int i0   = (unit & 15) * 128;
  const int bh   = unit >> 4;
  const int tid  = threadIdx.x;
  const int lane = tid & 63, wv = tid >> 6;
  const int l15 = lane & 15, l4 = lane >> 4;
  const float* Pb = pop + (size_t)bh * T_ * D_;
  float*       Ob = out + (size_t)bh * T_ * T_;
  const int ib0 = i0 + wv * 32;           // wave's 32 rows

  // ---- Phase A: scan rows ib0..ib0+31 -> Gs[row_local][d] (bf16) ----
  {
    const int d = lane;                   // lane == feature dim
    const float* P = Pb + d;

    // window-init sum for row ib0 (8 independent partial chains)
    int s0 = ib0 - (W_ - 1); if (s0 < 0) s0 = 0;
    const int jend = ib0 + 1;
    float p0=0.f,p1=0.f,p2=0.f,p3=0.f,p4=0.f,p5=0.f,p6=0.f,p7=0.f;
    int j = s0;
    for (; j + 8 <= jend; j += 8) {
      p0 += P[(size_t)(j+0)*D_]; p1 += P[(size_t)(j+1)*D_];
      p2 += P[(size_t)(j+2)*D_]; p3 += P[(size_t)(j+3)*D_];
      p4 += P[(size_t)(j+4)*D_]; p5 += P[(size_t)(j+5)*D_];
      p6 += P[(size_t)(j+6)*D_]; p7 += P[(size_t)(j+7)*D_];
    }
    for (; j < jend; ++j) p0 += P[(size_t)j*D_];
    const float isum0 = ((p0+p1)+(p2+p3)) + ((p4+p5)+(p6+p7));

    // preload arriving/departing values (independent loads, register arrays)
    float arrv[32], depv[32];
    arrv[0] = 0.f; depv[0] = 0.f;
    #pragma unroll
    for (int r = 1; r < 32; ++r) arrv[r] = P[(size_t)(ib0 + r) * D_];
    #pragma unroll
    for (int r = 1; r < 32; ++r) {
      const int jd = ib0 + r - W_;
      depv[r] = (jd >= 0) ? P[(size_t)jd * D_] : 0.f;
    }

    // serial part: 32-add prefix; everything after is independent per row
    float rinv[32];
    float run = isum0;
    #pragma unroll
    for (int r = 0; r < 32; ++r) {
      run += arrv[r] - depv[r];
      const int i = ib0 + r;
      const float cnt = (i + 1 < W_) ? (float)(i + 1) : (float)W_;
      rinv[r] = 1.0f / (run / cnt + 0.5f);
    }

    // 32 independent 64-lane allreduces (shuffles pipeline across rows)
    float sv[32];
    #pragma unroll
    for (int r = 0; r < 32; ++r) sv[r] = rinv[r];
    #pragma unroll
    for (int m = 32; m >= 1; m >>= 1) {
      #pragma unroll
      for (int r = 0; r < 32; ++r) sv[r] += __shfl_xor(sv[r], m);
    }

    #pragma unroll
    for (int r = 0; r < 32; ++r) {
      const int i = ib0 + r;
      const float cnt = (i + 1 < W_) ? (float)(i + 1) : (float)W_;
      float rowsum = cnt * (64.0f / sv[r] - 0.5f);
      rowsum = fmaxf(rowsum, 1e-10f);
      Gs[(wv * 32 + r) * GP + d] = f2bf(rinv[r] / (rowsum * sv[r]));
    }
  }
  __syncthreads();

  // ---- Phase B: band MFMA ----
  const bf16x8 g00 = *reinterpret_cast<const bf16x8*>(&Gs[(wv*32      + l15) * GP      + l4*8]);
  const bf16x8 g01 = *reinterpret_cast<const bf16x8*>(&Gs[(wv*32      + l15) * GP + 32 + l4*8]);
  const bf16x8 g10 = *reinterpret_cast<const bf16x8*>(&Gs[(wv*32 + 16 + l15) * GP      + l4*8]);
  const bf16x8 g11 = *reinterpret_cast<const bf16x8*>(&Gs[(wv*32 + 16 + l15) * GP + 32 + l4*8]);

  for (int jt = 0; jt < 24; ++jt) {
    const int jb = i0 - 256 + jt * 16;
    if (jb < 0) continue;                 // uniform across block
    const float* prow = &Pb[(size_t)(jb + l15) * D_];
    const f32x4 q0 = *reinterpret_cast<const f32x4*>(prow + l4*8);
    const f32x4 q1 = *reinterpret_cast<const f32x4*>(prow + l4*8 + 4);
    const f32x4 q2 = *reinterpret_cast<const f32x4*>(prow + 32 + l4*8);
    const f32x4 q3 = *reinterpret_cast<const f32x4*>(prow + 32 + l4*8 + 4);
    const bf16x8 p0 = cvt8(q0, q1);       // k = l4*8 .. +7
    const bf16x8 p1 = cvt8(q2, q3);       // k = 32 + l4*8 .. +7

    f32x4 c0 = {0.f, 0.f, 0.f, 0.f};
    f32x4 c1 = {0.f, 0.f, 0.f, 0.f};
    c0 = __builtin_amdgcn_mfma_f32_16x16x32_bf16(p0, g00, c0, 0, 0, 0);
    c0 = __builtin_amdgcn_mfma_f32_16x16x32_bf16(p1, g01, c0, 0, 0, 0);
    c1 = __builtin_amdgcn_mfma_f32_16x16x32_bf16(p0, g10, c1, 0, 0, 0);
    c1 = __builtin_amdgcn_mfma_f32_16x16x32_bf16(p1, g11, c1, 0, 0, 0);

    const int jq = jb + l4 * 4;           // 4 consecutive out-cols per lane
    {
      const int i = ib0 + l15;
      f32x4 v;
      #pragma unroll
      for (int r = 0; r < 4; ++r)
        v[r] = ((unsigned)(i - (jq + r)) < 256u) ? c0[r] : 0.f;
      *reinterpret_cast<f32x4*>(&Ob[(size_t)i * T_ + jq]) = v;   // regular: L2 merges
    }
    {
      const int i = ib0 + 16 + l15;
      f32x4 v;
      #pragma unroll
      for (int r = 0; r < 4; ++r)
        v[r] = ((unsigned)(i - (jq + r)) < 256u) ? c1[r] : 0.f;
      *reinterpret_cast<f32x4*>(&Ob[(size_t)i * T_ + jq]) = v;
    }
  }

  // ---- Phase 0 (last): zero segments outside [max(i0-256,0), i0+128) ----
  {
    int Lz = i0 - 256; if (Lz < 0) Lz = 0;
    const int L4n = Lz >> 2;
    const int R   = i0 + 128;
    const int W4r = (T_ - R) >> 2;
    const f32x4 z4 = {0.f, 0.f, 0.f, 0.f};
    for (int r = 0; r < 32; ++r) {
      float* orow = Ob + (size_t)(ib0 + r) * T_;
      f32x4* oL = reinterpret_cast<f32x4*>(orow);
      for (int c = lane; c < L4n; c += 64)
        __builtin_nontemporal_store(z4, &oL[c]);
      f32x4* oR = reinterpret_cast<f32x4*>(orow + R);
      for (int c = lane; c < W4r; c += 64)
        __builtin_nontemporal_store(z4, &oR[c]);
    }
  }
}

extern "C" void kernel_launch(void* const* d_in, const int* in_sizes, int n_in,
                              void* d_out, int out_size, void* d_ws, size_t ws_size,
                              hipStream_t stream) {
  const float* pop = (const float*)d_in[0];
  float* out = (float*)d_out;
  dim3 blk(256);
  hipLaunchKernelGGL(fused_strip, dim3(16 * BH_), blk, 0, stream, pop, out);
}

// Round 11
// 118.443 us; speedup vs baseline: 1.6810x; 1.1191x over previous
//
#include <hip/hip_runtime.h>
#include <cstdint>

#define T_  2048
#define D_  64
#define BH_ 32
#define W_  256
#define GP  72   // LDS row pitch in shorts (144 B)

typedef float f32x4 __attribute__((ext_vector_type(4)));
using bf16x8 = __attribute__((ext_vector_type(8))) short;   // 8 bf16 in 4 VGPRs

__device__ inline unsigned short f2bf(float x) {            // RNE fp32->bf16
  unsigned u = __float_as_uint(x);
  u = (u + 0x7fffu + ((u >> 16) & 1u)) >> 16;
  return (unsigned short)u;
}

__device__ inline bf16x8 cvt8(const f32x4 lo, const f32x4 hi) {
  bf16x8 r;
  r[0] = (short)f2bf(lo.x); r[1] = (short)f2bf(lo.y);
  r[2] = (short)f2bf(lo.z); r[3] = (short)f2bf(lo.w);
  r[4] = (short)f2bf(hi.x); r[5] = (short)f2bf(hi.y);
  r[6] = (short)f2bf(hi.z); r[7] = (short)f2bf(hi.w);
  return r;
}

// One block (512 thr) per (bh, 128-row strip). Wave-specialized roles:
//  waves 0-3: sliding-window scan -> gene fitness -> bf16 LDS (each wave's Gs
//             rows are private to it -> NO __syncthreads needed), then banded
//             GEMM via swapped-operand mfma_16x16x32_bf16, regular f32x4
//             stores (L2 merges 64B row segments into full lines).
//  waves 4-7: stream zeros (NT, full 1KB lines) to the out-of-band segments,
//             starting at t=0. Separate waves = separate vmcnt counters, so
//             the zero-store backlog never gates the band waves' loads, and
//             the store pipe stays busy for the entire kernel duration.
__global__ __launch_bounds__(512, 2) void fused_strip(const float* __restrict__ pop,
                                                      float* __restrict__ out) {
  __shared__ unsigned short Gs[128 * GP];
  const int unit = blockIdx.x;            // 0..511
  const int i0   = (unit & 15) * 128;
  const int bh   = unit >> 4;
  const int tid  = threadIdx.x;
  const int lane = tid & 63, wv = tid >> 6;   // wv: 0..7
  const float* Pb = pop + (size_t)bh * T_ * D_;
  float*       Ob = out + (size_t)bh * T_ * T_;

  if (wv >= 4) {
    // -------- zero role: rows i0+(wv-4)*32 .. +31 --------
    const int rb = i0 + (wv - 4) * 32;
    int Lz = i0 - 256; if (Lz < 0) Lz = 0;
    const int L4n = Lz >> 2;
    const int R   = i0 + 128;
    const int W4r = (T_ - R) >> 2;
    const f32x4 z4 = {0.f, 0.f, 0.f, 0.f};
    for (int r = 0; r < 32; ++r) {
      float* orow = Ob + (size_t)(rb + r) * T_;
      f32x4* oL = reinterpret_cast<f32x4*>(orow);
      for (int c = lane; c < L4n; c += 64)
        __builtin_nontemporal_store(z4, &oL[c]);
      f32x4* oR = reinterpret_cast<f32x4*>(orow + R);
      for (int c = lane; c < W4r; c += 64)
        __builtin_nontemporal_store(z4, &oR[c]);
    }
    return;
  }

  // -------- band role: wave wv owns rows ib0..ib0+31 --------
  const int l15 = lane & 15, l4 = lane >> 4;
  const int ib0 = i0 + wv * 32;

  // ---- scan (chunked, register-lean): rows ib0..ib0+31 -> Gs (bf16) ----
  {
    const int d = lane;                   // lane == feature dim
    const float* P = Pb + d;

    int s0 = ib0 - (W_ - 1); if (s0 < 0) s0 = 0;
    const int jend = ib0 + 1;
    float p0=0.f,p1=0.f,p2=0.f,p3=0.f,p4=0.f,p5=0.f,p6=0.f,p7=0.f;
    int j = s0;
    for (; j + 8 <= jend; j += 8) {
      p0 += P[(size_t)(j+0)*D_]; p1 += P[(size_t)(j+1)*D_];
      p2 += P[(size_t)(j+2)*D_]; p3 += P[(size_t)(j+3)*D_];
      p4 += P[(size_t)(j+4)*D_]; p5 += P[(size_t)(j+5)*D_];
      p6 += P[(size_t)(j+6)*D_]; p7 += P[(size_t)(j+7)*D_];
    }
    for (; j < jend; ++j) p0 += P[(size_t)j*D_];
    float run = ((p0+p1)+(p2+p3)) + ((p4+p5)+(p6+p7));   // window sum @ row ib0

    #pragma unroll
    for (int c = 0; c < 4; ++c) {         // 4 chunks x 8 rows
      float av[8], dv[8];
      #pragma unroll
      for (int k = 0; k < 8; ++k) {
        const int r = c * 8 + k;
        av[k] = (r == 0) ? 0.f : P[(size_t)(ib0 + r) * D_];
        const int jd = ib0 + r - W_;
        dv[k] = (r == 0 || jd < 0) ? 0.f : P[(size_t)jd * D_];
      }
      float rinv[8], sv[8];
      #pragma unroll
      for (int k = 0; k < 8; ++k) {
        run += av[k] - dv[k];
        const int i = ib0 + c * 8 + k;
        const float cnt = (i + 1 < W_) ? (float)(i + 1) : (float)W_;
        rinv[k] = 1.0f / (run / cnt + 0.5f);
        sv[k] = rinv[k];
      }
      #pragma unroll
      for (int m = 32; m >= 1; m >>= 1) {
        #pragma unroll
        for (int k = 0; k < 8; ++k) sv[k] += __shfl_xor(sv[k], m);
      }
      #pragma unroll
      for (int k = 0; k < 8; ++k) {
        const int i = ib0 + c * 8 + k;
        const float cnt = (i + 1 < W_) ? (float)(i + 1) : (float)W_;
        float rowsum = cnt * (64.0f / sv[k] - 0.5f);
        rowsum = fmaxf(rowsum, 1e-10f);
        Gs[(wv * 32 + c * 8 + k) * GP + d] = f2bf(rinv[k] / (rowsum * sv[k]));
      }
    }
  }
  // intra-wave LDS write->read ordering handled by compiler lgkmcnt waits

  // ---- band MFMA: gfs fragments from this wave's own Gs rows ----
  const bf16x8 g00 = *reinterpret_cast<const bf16x8*>(&Gs[(wv*32      + l15) * GP      + l4*8]);
  const bf16x8 g01 = *reinterpret_cast<const bf16x8*>(&Gs[(wv*32      + l15) * GP + 32 + l4*8]);
  const bf16x8 g10 = *reinterpret_cast<const bf16x8*>(&Gs[(wv*32 + 16 + l15) * GP      + l4*8]);
  const bf16x8 g11 = *reinterpret_cast<const bf16x8*>(&Gs[(wv*32 + 16 + l15) * GP + 32 + l4*8]);

  for (int jt = 0; jt < 24; ++jt) {
    const int jb = i0 - 256 + jt * 16;
    if (jb < 0) continue;                 // uniform across the wave
    const float* prow = &Pb[(size_t)(jb + l15) * D_];
    const f32x4 q0 = *reinterpret_cast<const f32x4*>(prow + l4*8);
    const f32x4 q1 = *reinterpret_cast<const f32x4*>(prow + l4*8 + 4);
    const f32x4 q2 = *reinterpret_cast<const f32x4*>(prow + 32 + l4*8);
    const f32x4 q3 = *reinterpret_cast<const f32x4*>(prow + 32 + l4*8 + 4);
    const bf16x8 p0 = cvt8(q0, q1);       // k = l4*8 .. +7
    const bf16x8 p1 = cvt8(q2, q3);       // k = 32 + l4*8 .. +7

    f32x4 c0 = {0.f, 0.f, 0.f, 0.f};
    f32x4 c1 = {0.f, 0.f, 0.f, 0.f};
    c0 = __builtin_amdgcn_mfma_f32_16x16x32_bf16(p0, g00, c0, 0, 0, 0);
    c0 = __builtin_amdgcn_mfma_f32_16x16x32_bf16(p1, g01, c0, 0, 0, 0);
    c1 = __builtin_amdgcn_mfma_f32_16x16x32_bf16(p0, g10, c1, 0, 0, 0);
    c1 = __builtin_amdgcn_mfma_f32_16x16x32_bf16(p1, g11, c1, 0, 0, 0);

    const int jq = jb + l4 * 4;           // 4 consecutive out-cols per lane
    {
      const int i = ib0 + l15;
      f32x4 v;
      #pragma unroll
      for (int r = 0; r < 4; ++r)
        v[r] = ((unsigned)(i - (jq + r)) < 256u) ? c0[r] : 0.f;
      *reinterpret_cast<f32x4*>(&Ob[(size_t)i * T_ + jq]) = v;   // regular: L2 merges
    }
    {
      const int i = ib0 + 16 + l15;
      f32x4 v;
      #pragma unroll
      for (int r = 0; r < 4; ++r)
        v[r] = ((unsigned)(i - (jq + r)) < 256u) ? c1[r] : 0.f;
      *reinterpret_cast<f32x4*>(&Ob[(size_t)i * T_ + jq]) = v;
    }
  }
}

extern "C" void kernel_launch(void* const* d_in, const int* in_sizes, int n_in,
                              void* d_out, int out_size, void* d_ws, size_t ws_size,
                              hipStream_t stream) {
  const float* pop = (const float*)d_in[0];
  float* out = (float*)d_out;
  dim3 blk(512);
  hipLaunchKernelGGL(fused_strip, dim3(16 * BH_), blk, 0, stream, pop, out);
}

// Round 12
// 114.973 us; speedup vs baseline: 1.7317x; 1.0302x over previous
//
#include <hip/hip_runtime.h>
#include <cstdint>

#define T_  2048
#define D_  64
#define BH_ 32
#define W_  256
#define GP  72   // LDS row pitch in shorts (144 B)

typedef float f32x4 __attribute__((ext_vector_type(4)));
using bf16x8 = __attribute__((ext_vector_type(8))) short;   // 8 bf16 in 4 VGPRs

__device__ inline unsigned short f2bf(float x) {            // RNE fp32->bf16
  unsigned u = __float_as_uint(x);
  u = (u + 0x7fffu + ((u >> 16) & 1u)) >> 16;
  return (unsigned short)u;
}

__device__ inline bf16x8 cvt8(const f32x4 lo, const f32x4 hi) {
  bf16x8 r;
  r[0] = (short)f2bf(lo.x); r[1] = (short)f2bf(lo.y);
  r[2] = (short)f2bf(lo.z); r[3] = (short)f2bf(lo.w);
  r[4] = (short)f2bf(hi.x); r[5] = (short)f2bf(hi.y);
  r[6] = (short)f2bf(hi.z); r[7] = (short)f2bf(hi.w);
  return r;
}

// One block (512 thr) per (bh, 128-row strip). Wave-specialized roles:
//  waves 0-3: sliding-window scan -> gene fitness -> bf16 LDS (wave-private Gs
//             rows, no __syncthreads), then banded GEMM via swapped-operand
//             mfma_16x16x32_bf16, regular f32x4 stores (L2-merged).
//  waves 4-7: stream zeros (NT) to the out-of-band segments. Rows are
//             INTERLEAVED mod 4 across the 4 waves so their address streams
//             leapfrog at 8KB spacing -> one ~coherent monotone sweep per
//             block (~512 machine-wide streams instead of 2048) for DRAM page
//             locality. Separate waves = separate vmcnt, so the store backlog
//             never gates band-wave loads.
__global__ __launch_bounds__(512, 2) void fused_strip(const float* __restrict__ pop,
                                                      float* __restrict__ out) {
  __shared__ unsigned short Gs[128 * GP];
  const int unit = blockIdx.x;            // 0..511
  const int i0   = (unit & 15) * 128;
  const int bh   = unit >> 4;
  const int tid  = threadIdx.x;
  const int lane = tid & 63, wv = tid >> 6;   // wv: 0..7
  const float* Pb = pop + (size_t)bh * T_ * D_;
  float*       Ob = out + (size_t)bh * T_ * T_;

  if (wv >= 4) {
    // -------- zero role: rows r == (wv-4) mod 4, coherent leapfrog sweep ----
    const int q = wv - 4;
    int Lz = i0 - 256; if (Lz < 0) Lz = 0;
    const int L4n = Lz >> 2;
    const int R   = i0 + 128;
    const int W4r = (T_ - R) >> 2;
    const f32x4 z4 = {0.f, 0.f, 0.f, 0.f};
    for (int r = q; r < 128; r += 4) {
      float* orow = Ob + (size_t)(i0 + r) * T_;
      f32x4* oL = reinterpret_cast<f32x4*>(orow);
      for (int c = lane; c < L4n; c += 64)
        __builtin_nontemporal_store(z4, &oL[c]);
      f32x4* oR = reinterpret_cast<f32x4*>(orow + R);
      for (int c = lane; c < W4r; c += 64)
        __builtin_nontemporal_store(z4, &oR[c]);
    }
    return;
  }

  // -------- band role: wave wv owns rows ib0..ib0+31 --------
  const int l15 = lane & 15, l4 = lane >> 4;
  const int ib0 = i0 + wv * 32;

  // ---- scan (chunked, register-lean): rows ib0..ib0+31 -> Gs (bf16) ----
  {
    const int d = lane;                   // lane == feature dim
    const float* P = Pb + d;

    int s0 = ib0 - (W_ - 1); if (s0 < 0) s0 = 0;
    const int jend = ib0 + 1;
    float p0=0.f,p1=0.f,p2=0.f,p3=0.f,p4=0.f,p5=0.f,p6=0.f,p7=0.f;
    int j = s0;
    for (; j + 8 <= jend; j += 8) {
      p0 += P[(size_t)(j+0)*D_]; p1 += P[(size_t)(j+1)*D_];
      p2 += P[(size_t)(j+2)*D_]; p3 += P[(size_t)(j+3)*D_];
      p4 += P[(size_t)(j+4)*D_]; p5 += P[(size_t)(j+5)*D_];
      p6 += P[(size_t)(j+6)*D_]; p7 += P[(size_t)(j+7)*D_];
    }
    for (; j < jend; ++j) p0 += P[(size_t)j*D_];
    float run = ((p0+p1)+(p2+p3)) + ((p4+p5)+(p6+p7));   // window sum @ row ib0

    #pragma unroll
    for (int c = 0; c < 4; ++c) {         // 4 chunks x 8 rows
      float av[8], dv[8];
      #pragma unroll
      for (int k = 0; k < 8; ++k) {
        const int r = c * 8 + k;
        av[k] = (r == 0) ? 0.f : P[(size_t)(ib0 + r) * D_];
        const int jd = ib0 + r - W_;
        dv[k] = (r == 0 || jd < 0) ? 0.f : P[(size_t)jd * D_];
      }
      float rinv[8], sv[8];
      #pragma unroll
      for (int k = 0; k < 8; ++k) {
        run += av[k] - dv[k];
        const int i = ib0 + c * 8 + k;
        const float cnt = (i + 1 < W_) ? (float)(i + 1) : (float)W_;
        rinv[k] = 1.0f / (run / cnt + 0.5f);
        sv[k] = rinv[k];
      }
      #pragma unroll
      for (int m = 32; m >= 1; m >>= 1) {
        #pragma unroll
        for (int k = 0; k < 8; ++k) sv[k] += __shfl_xor(sv[k], m);
      }
      #pragma unroll
      for (int k = 0; k < 8; ++k) {
        const int i = ib0 + c * 8 + k;
        const float cnt = (i + 1 < W_) ? (float)(i + 1) : (float)W_;
        float rowsum = cnt * (64.0f / sv[k] - 0.5f);
        rowsum = fmaxf(rowsum, 1e-10f);
        Gs[(wv * 32 + c * 8 + k) * GP + d] = f2bf(rinv[k] / (rowsum * sv[k]));
      }
    }
  }
  // intra-wave LDS write->read ordering handled by compiler lgkmcnt waits

  // ---- band MFMA: gfs fragments from this wave's own Gs rows ----
  const bf16x8 g00 = *reinterpret_cast<const bf16x8*>(&Gs[(wv*32      + l15) * GP      + l4*8]);
  const bf16x8 g01 = *reinterpret_cast<const bf16x8*>(&Gs[(wv*32      + l15) * GP + 32 + l4*8]);
  const bf16x8 g10 = *reinterpret_cast<const bf16x8*>(&Gs[(wv*32 + 16 + l15) * GP      + l4*8]);
  const bf16x8 g11 = *reinterpret_cast<const bf16x8*>(&Gs[(wv*32 + 16 + l15) * GP + 32 + l4*8]);

  for (int jt = 0; jt < 24; ++jt) {
    const int jb = i0 - 256 + jt * 16;
    if (jb < 0) continue;                 // uniform across the wave
    const float* prow = &Pb[(size_t)(jb + l15) * D_];
    const f32x4 q0 = *reinterpret_cast<const f32x4*>(prow + l4*8);
    const f32x4 q1 = *reinterpret_cast<const f32x4*>(prow + l4*8 + 4);
    const f32x4 q2 = *reinterpret_cast<const f32x4*>(prow + 32 + l4*8);
    const f32x4 q3 = *reinterpret_cast<const f32x4*>(prow + 32 + l4*8 + 4);
    const bf16x8 p0 = cvt8(q0, q1);       // k = l4*8 .. +7
    const bf16x8 p1 = cvt8(q2, q3);       // k = 32 + l4*8 .. +7

    f32x4 c0 = {0.f, 0.f, 0.f, 0.f};
    f32x4 c1 = {0.f, 0.f, 0.f, 0.f};
    c0 = __builtin_amdgcn_mfma_f32_16x16x32_bf16(p0, g00, c0, 0, 0, 0);
    c0 = __builtin_amdgcn_mfma_f32_16x16x32_bf16(p1, g01, c0, 0, 0, 0);
    c1 = __builtin_amdgcn_mfma_f32_16x16x32_bf16(p0, g10, c1, 0, 0, 0);
    c1 = __builtin_amdgcn_mfma_f32_16x16x32_bf16(p1, g11, c1, 0, 0, 0);

    const int jq = jb + l4 * 4;           // 4 consecutive out-cols per lane
    {
      const int i = ib0 + l15;
      f32x4 v;
      #pragma unroll
      for (int r = 0; r < 4; ++r)
        v[r] = ((unsigned)(i - (jq + r)) < 256u) ? c0[r] : 0.f;
      *reinterpret_cast<f32x4*>(&Ob[(size_t)i * T_ + jq]) = v;   // regular: L2 merges
    }
    {
      const int i = ib0 + 16 + l15;
      f32x4 v;
      #pragma unroll
      for (int r = 0; r < 4; ++r)
        v[r] = ((unsigned)(i - (jq + r)) < 256u) ? c1[r] : 0.f;
      *reinterpret_cast<f32x4*>(&Ob[(size_t)i * T_ + jq]) = v;
    }
  }
}

extern "C" void kernel_launch(void* const* d_in, const int* in_sizes, int n_in,
                              void* d_out, int out_size, void* d_ws, size_t ws_size,
                              hipStream_t stream) {
  const float* pop = (const float*)d_in[0];
  float* out = (float*)d_out;
  dim3 blk(512);
  hipLaunchKernelGGL(fused_strip, dim3(16 * BH_), blk, 0, stream, pop, out);
}

// Round 13
// 114.884 us; speedup vs baseline: 1.7331x; 1.0008x over previous
//
#include <hip/hip_runtime.h>
#include <cstdint>

#define T_  2048
#define D_  64
#define BH_ 32
#define W_  256
#define GP  72   // LDS row pitch in shorts (144 B)

typedef float f32x4 __attribute__((ext_vector_type(4)));
using bf16x8 = __attribute__((ext_vector_type(8))) short;   // 8 bf16 in 4 VGPRs

__device__ inline unsigned short f2bf(float x) {            // RNE fp32->bf16
  unsigned u = __float_as_uint(x);
  u = (u + 0x7fffu + ((u >> 16) & 1u)) >> 16;
  return (unsigned short)u;
}

__device__ inline bf16x8 cvt8(const f32x4 lo, const f32x4 hi) {
  bf16x8 r;
  r[0] = (short)f2bf(lo.x); r[1] = (short)f2bf(lo.y);
  r[2] = (short)f2bf(lo.z); r[3] = (short)f2bf(lo.w);
  r[4] = (short)f2bf(hi.x); r[5] = (short)f2bf(hi.y);
  r[6] = (short)f2bf(hi.z); r[7] = (short)f2bf(hi.w);
  return r;
}

// One block (512 thr) per (bh, 128-row strip). Wave-specialized roles:
//  waves 0-3: sliding-window scan -> gene fitness -> bf16 LDS (wave-private Gs
//             rows, no __syncthreads), then banded GEMM via swapped-operand
//             mfma_16x16x32_bf16, regular f32x4 stores (L2-merged).
//  waves 4-7: stream zeros (NT) to the out-of-band segments. Rows are
//             INTERLEAVED mod 4 across the 4 waves so their address streams
//             leapfrog at 8KB spacing -> one ~coherent monotone sweep per
//             block (~512 machine-wide streams instead of 2048) for DRAM page
//             locality. Separate waves = separate vmcnt, so the store backlog
//             never gates band-wave loads.
__global__ __launch_bounds__(512, 2) void fused_strip(const float* __restrict__ pop,
                                                      float* __restrict__ out) {
  __shared__ unsigned short Gs[128 * GP];
  const int unit = blockIdx.x;            // 0..511
  const int i0   = (unit & 15) * 128;
  const int bh   = unit >> 4;
  const int tid  = threadIdx.x;
  const int lane = tid & 63, wv = tid >> 6;   // wv: 0..7
  const float* Pb = pop + (size_t)bh * T_ * D_;
  float*       Ob = out + (size_t)bh * T_ * T_;

  if (wv >= 4) {
    // -------- zero role: rows r == (wv-4) mod 4, coherent leapfrog sweep ----
    const int q = wv - 4;
    int Lz = i0 - 256; if (Lz < 0) Lz = 0;
    const int L4n = Lz >> 2;
    const int R   = i0 + 128;
    const int W4r = (T_ - R) >> 2;
    const f32x4 z4 = {0.f, 0.f, 0.f, 0.f};
    for (int r = q; r < 128; r += 4) {
      float* orow = Ob + (size_t)(i0 + r) * T_;
      f32x4* oL = reinterpret_cast<f32x4*>(orow);
      for (int c = lane; c < L4n; c += 64)
        __builtin_nontemporal_store(z4, &oL[c]);
      f32x4* oR = reinterpret_cast<f32x4*>(orow + R);
      for (int c = lane; c < W4r; c += 64)
        __builtin_nontemporal_store(z4, &oR[c]);
    }
    return;
  }

  // -------- band role: wave wv owns rows ib0..ib0+31 --------
  const int l15 = lane & 15, l4 = lane >> 4;
  const int ib0 = i0 + wv * 32;

  // ---- scan (chunked, register-lean): rows ib0..ib0+31 -> Gs (bf16) ----
  {
    const int d = lane;                   // lane == feature dim
    const float* P = Pb + d;

    int s0 = ib0 - (W_ - 1); if (s0 < 0) s0 = 0;
    const int jend = ib0 + 1;
    float p0=0.f,p1=0.f,p2=0.f,p3=0.f,p4=0.f,p5=0.f,p6=0.f,p7=0.f;
    int j = s0;
    for (; j + 8 <= jend; j += 8) {
      p0 += P[(size_t)(j+0)*D_]; p1 += P[(size_t)(j+1)*D_];
      p2 += P[(size_t)(j+2)*D_]; p3 += P[(size_t)(j+3)*D_];
      p4 += P[(size_t)(j+4)*D_]; p5 += P[(size_t)(j+5)*D_];
      p6 += P[(size_t)(j+6)*D_]; p7 += P[(size_t)(j+7)*D_];
    }
    for (; j < jend; ++j) p0 += P[(size_t)j*D_];
    float run = ((p0+p1)+(p2+p3)) + ((p4+p5)+(p6+p7));   // window sum @ row ib0

    #pragma unroll
    for (int c = 0; c < 4; ++c) {         // 4 chunks x 8 rows
      float av[8], dv[8];
      #pragma unroll
      for (int k = 0; k < 8; ++k) {
        const int r = c * 8 + k;
        av[k] = (r == 0) ? 0.f : P[(size_t)(ib0 + r) * D_];
        const int jd = ib0 + r - W_;
        dv[k] = (r == 0 || jd < 0) ? 0.f : P[(size_t)jd * D_];
      }
      float rinv[8], sv[8];
      #pragma unroll
      for (int k = 0; k < 8; ++k) {
        run += av[k] - dv[k];
        const int i = ib0 + c * 8 + k;
        const float cnt = (i + 1 < W_) ? (float)(i + 1) : (float)W_;
        rinv[k] = 1.0f / (run / cnt + 0.5f);
        sv[k] = rinv[k];
      }
      #pragma unroll
      for (int m = 32; m >= 1; m >>= 1) {
        #pragma unroll
        for (int k = 0; k < 8; ++k) sv[k] += __shfl_xor(sv[k], m);
      }
      #pragma unroll
      for (int k = 0; k < 8; ++k) {
        const int i = ib0 + c * 8 + k;
        const float cnt = (i + 1 < W_) ? (float)(i + 1) : (float)W_;
        float rowsum = cnt * (64.0f / sv[k] - 0.5f);
        rowsum = fmaxf(rowsum, 1e-10f);
        Gs[(wv * 32 + c * 8 + k) * GP + d] = f2bf(rinv[k] / (rowsum * sv[k]));
      }
    }
  }
  // intra-wave LDS write->read ordering handled by compiler lgkmcnt waits

  // ---- band MFMA: gfs fragments from this wave's own Gs rows ----
  const bf16x8 g00 = *reinterpret_cast<const bf16x8*>(&Gs[(wv*32      + l15) * GP      + l4*8]);
  const bf16x8 g01 = *reinterpret_cast<const bf16x8*>(&Gs[(wv*32      + l15) * GP + 32 + l4*8]);
  const bf16x8 g10 = *reinterpret_cast<const bf16x8*>(&Gs[(wv*32 + 16 + l15) * GP      + l4*8]);
  const bf16x8 g11 = *reinterpret_cast<const bf16x8*>(&Gs[(wv*32 + 16 + l15) * GP + 32 + l4*8]);

  for (int jt = 0; jt < 24; ++jt) {
    const int jb = i0 - 256 + jt * 16;
    if (jb < 0) continue;                 // uniform across the wave
    const float* prow = &Pb[(size_t)(jb + l15) * D_];
    const f32x4 q0 = *reinterpret_cast<const f32x4*>(prow + l4*8);
    const f32x4 q1 = *reinterpret_cast<const f32x4*>(prow + l4*8 + 4);
    const f32x4 q2 = *reinterpret_cast<const f32x4*>(prow + 32 + l4*8);
    const f32x4 q3 = *reinterpret_cast<const f32x4*>(prow + 32 + l4*8 + 4);
    const bf16x8 p0 = cvt8(q0, q1);       // k = l4*8 .. +7
    const bf16x8 p1 = cvt8(q2, q3);       // k = 32 + l4*8 .. +7

    f32x4 c0 = {0.f, 0.f, 0.f, 0.f};
    f32x4 c1 = {0.f, 0.f, 0.f, 0.f};
    c0 = __builtin_amdgcn_mfma_f32_16x16x32_bf16(p0, g00, c0, 0, 0, 0);
    c0 = __builtin_amdgcn_mfma_f32_16x16x32_bf16(p1, g01, c0, 0, 0, 0);
    c1 = __builtin_amdgcn_mfma_f32_16x16x32_bf16(p0, g10, c1, 0, 0, 0);
    c1 = __builtin_amdgcn_mfma_f32_16x16x32_bf16(p1, g11, c1, 0, 0, 0);

    const int jq = jb + l4 * 4;           // 4 consecutive out-cols per lane
    {
      const int i = ib0 + l15;
      f32x4 v;
      #pragma unroll
      for (int r = 0; r < 4; ++r)
        v[r] = ((unsigned)(i - (jq + r)) < 256u) ? c0[r] : 0.f;
      *reinterpret_cast<f32x4*>(&Ob[(size_t)i * T_ + jq]) = v;   // regular: L2 merges
    }
    {
      const int i = ib0 + 16 + l15;
      f32x4 v;
      #pragma unroll
      for (int r = 0; r < 4; ++r)
        v[r] = ((unsigned)(i - (jq + r)) < 256u) ? c1[r] : 0.f;
      *reinterpret_cast<f32x4*>(&Ob[(size_t)i * T_ + jq]) = v;
    }
  }
}

extern "C" void kernel_launch(void* const* d_in, const int* in_sizes, int n_in,
                              void* d_out, int out_size, void* d_ws, size_t ws_size,
                              hipStream_t stream) {
  const float* pop = (const float*)d_in[0];
  float* out = (float*)d_out;
  dim3 blk(512);
  hipLaunchKernelGGL(fused_strip, dim3(16 * BH_), blk, 0, stream, pop, out);
}

// Round 14
// 114.656 us; speedup vs baseline: 1.7365x; 1.0020x over previous
//
#include <hip/hip_runtime.h>
#include <cstdint>

#define T_  2048
#define D_  64
#define BH_ 32
#define W_  256
#define GP  72   // LDS row pitch in shorts (144 B)

typedef float f32x4 __attribute__((ext_vector_type(4)));
using bf16x8 = __attribute__((ext_vector_type(8))) short;   // 8 bf16 in 4 VGPRs

__device__ inline unsigned short f2bf(float x) {            // RNE fp32->bf16
  unsigned u = __float_as_uint(x);
  u = (u + 0x7fffu + ((u >> 16) & 1u)) >> 16;
  return (unsigned short)u;
}

__device__ inline bf16x8 cvt8(const f32x4 lo, const f32x4 hi) {
  bf16x8 r;
  r[0] = (short)f2bf(lo.x); r[1] = (short)f2bf(lo.y);
  r[2] = (short)f2bf(lo.z); r[3] = (short)f2bf(lo.w);
  r[4] = (short)f2bf(hi.x); r[5] = (short)f2bf(hi.y);
  r[6] = (short)f2bf(hi.z); r[7] = (short)f2bf(hi.w);
  return r;
}

// One block (512 thr) per (bh, 128-row strip). Wave-specialized roles:
//  waves 0-3: scan -> gene fitness -> bf16 LDS (wave-private rows), then
//             banded GEMM via swapped-operand mfma_16x16x32_bf16, regular
//             f32x4 stores (L2-merged).
//  waves 4-7: NT zero streaming of out-of-band segments, rows interleaved
//             mod 4 (coherent leapfrog sweep), separate vmcnt from band waves.
// __launch_bounds__(512, 4): VGPR cap 128 -> guarantees 2 blocks/CU so the
// whole 512-block grid is resident in ONE pass (residency was the suspected
// limiter at (512,2)).
__global__ __launch_bounds__(512, 4) void fused_strip(const float* __restrict__ pop,
                                                      float* __restrict__ out) {
  __shared__ unsigned short Gs[128 * GP];
  const int unit = blockIdx.x;            // 0..511
  const int i0   = (unit & 15) * 128;
  const int bh   = unit >> 4;
  const int tid  = threadIdx.x;
  const int lane = tid & 63, wv = tid >> 6;   // wv: 0..7
  const float* Pb = pop + (size_t)bh * T_ * D_;
  float*       Ob = out + (size_t)bh * T_ * T_;

  if (wv >= 4) {
    // -------- zero role: rows r == (wv-4) mod 4, coherent leapfrog sweep ----
    const int q = wv - 4;
    int Lz = i0 - 256; if (Lz < 0) Lz = 0;
    const int L4n = Lz >> 2;
    const int R   = i0 + 128;
    const int W4r = (T_ - R) >> 2;
    const f32x4 z4 = {0.f, 0.f, 0.f, 0.f};
    for (int r = q; r < 128; r += 4) {
      float* orow = Ob + (size_t)(i0 + r) * T_;
      f32x4* oL = reinterpret_cast<f32x4*>(orow);
      for (int c = lane; c < L4n; c += 64)
        __builtin_nontemporal_store(z4, &oL[c]);
      f32x4* oR = reinterpret_cast<f32x4*>(orow + R);
      for (int c = lane; c < W4r; c += 64)
        __builtin_nontemporal_store(z4, &oR[c]);
    }
    return;
  }

  // -------- band role: wave wv owns rows ib0..ib0+31 --------
  const int l15 = lane & 15, l4 = lane >> 4;
  const int ib0 = i0 + wv * 32;

  // ---- scan (chunked, register-lean): rows ib0..ib0+31 -> Gs (bf16) ----
  {
    const int d = lane;                   // lane == feature dim
    const float* P = Pb + d;

    int s0 = ib0 - (W_ - 1); if (s0 < 0) s0 = 0;
    const int jend = ib0 + 1;
    float p0=0.f,p1=0.f,p2=0.f,p3=0.f,p4=0.f,p5=0.f,p6=0.f,p7=0.f;
    int j = s0;
    for (; j + 8 <= jend; j += 8) {
      p0 += P[(size_t)(j+0)*D_]; p1 += P[(size_t)(j+1)*D_];
      p2 += P[(size_t)(j+2)*D_]; p3 += P[(size_t)(j+3)*D_];
      p4 += P[(size_t)(j+4)*D_]; p5 += P[(size_t)(j+5)*D_];
      p6 += P[(size_t)(j+6)*D_]; p7 += P[(size_t)(j+7)*D_];
    }
    for (; j < jend; ++j) p0 += P[(size_t)j*D_];
    float run = ((p0+p1)+(p2+p3)) + ((p4+p5)+(p6+p7));   // window sum @ row ib0

    #pragma unroll
    for (int c = 0; c < 4; ++c) {         // 4 chunks x 8 rows
      float av[8], dv[8];
      #pragma unroll
      for (int k = 0; k < 8; ++k) {
        const int r = c * 8 + k;
        av[k] = (r == 0) ? 0.f : P[(size_t)(ib0 + r) * D_];
        const int jd = ib0 + r - W_;
        dv[k] = (r == 0 || jd < 0) ? 0.f : P[(size_t)jd * D_];
      }
      float rinv[8], sv[8];
      #pragma unroll
      for (int k = 0; k < 8; ++k) {
        run += av[k] - dv[k];
        const int i = ib0 + c * 8 + k;
        const float cnt = (i + 1 < W_) ? (float)(i + 1) : (float)W_;
        rinv[k] = 1.0f / (run / cnt + 0.5f);
        sv[k] = rinv[k];
      }
      #pragma unroll
      for (int m = 32; m >= 1; m >>= 1) {
        #pragma unroll
        for (int k = 0; k < 8; ++k) sv[k] += __shfl_xor(sv[k], m);
      }
      #pragma unroll
      for (int k = 0; k < 8; ++k) {
        const int i = ib0 + c * 8 + k;
        const float cnt = (i + 1 < W_) ? (float)(i + 1) : (float)W_;
        float rowsum = cnt * (64.0f / sv[k] - 0.5f);
        rowsum = fmaxf(rowsum, 1e-10f);
        Gs[(wv * 32 + c * 8 + k) * GP + d] = f2bf(rinv[k] / (rowsum * sv[k]));
      }
    }
  }
  // intra-wave LDS write->read ordering handled by compiler lgkmcnt waits

  // ---- band MFMA: gfs fragments from this wave's own Gs rows ----
  const bf16x8 g00 = *reinterpret_cast<const bf16x8*>(&Gs[(wv*32      + l15) * GP      + l4*8]);
  const bf16x8 g01 = *reinterpret_cast<const bf16x8*>(&Gs[(wv*32      + l15) * GP + 32 + l4*8]);
  const bf16x8 g10 = *reinterpret_cast<const bf16x8*>(&Gs[(wv*32 + 16 + l15) * GP      + l4*8]);
  const bf16x8 g11 = *reinterpret_cast<const bf16x8*>(&Gs[(wv*32 + 16 + l15) * GP + 32 + l4*8]);

  for (int jt = 0; jt < 24; ++jt) {
    const int jb = i0 - 256 + jt * 16;
    if (jb < 0) continue;                 // uniform across the wave
    const float* prow = &Pb[(size_t)(jb + l15) * D_];
    const f32x4 q0 = *reinterpret_cast<const f32x4*>(prow + l4*8);
    const f32x4 q1 = *reinterpret_cast<const f32x4*>(prow + l4*8 + 4);
    const f32x4 q2 = *reinterpret_cast<const f32x4*>(prow + 32 + l4*8);
    const f32x4 q3 = *reinterpret_cast<const f32x4*>(prow + 32 + l4*8 + 4);
    const bf16x8 p0 = cvt8(q0, q1);       // k = l4*8 .. +7
    const bf16x8 p1 = cvt8(q2, q3);       // k = 32 + l4*8 .. +7

    f32x4 c0 = {0.f, 0.f, 0.f, 0.f};
    f32x4 c1 = {0.f, 0.f, 0.f, 0.f};
    c0 = __builtin_amdgcn_mfma_f32_16x16x32_bf16(p0, g00, c0, 0, 0, 0);
    c0 = __builtin_amdgcn_mfma_f32_16x16x32_bf16(p1, g01, c0, 0, 0, 0);
    c1 = __builtin_amdgcn_mfma_f32_16x16x32_bf16(p0, g10, c1, 0, 0, 0);
    c1 = __builtin_amdgcn_mfma_f32_16x16x32_bf16(p1, g11, c1, 0, 0, 0);

    const int jq = jb + l4 * 4;           // 4 consecutive out-cols per lane
    {
      const int i = ib0 + l15;
      f32x4 v;
      #pragma unroll
      for (int r = 0; r < 4; ++r)
        v[r] = ((unsigned)(i - (jq + r)) < 256u) ? c0[r] : 0.f;
      *reinterpret_cast<f32x4*>(&Ob[(size_t)i * T_ + jq]) = v;   // regular: L2 merges
    }
    {
      const int i = ib0 + 16 + l15;
      f32x4 v;
      #pragma unroll
      for (int r = 0; r < 4; ++r)
        v[r] = ((unsigned)(i - (jq + r)) < 256u) ? c1[r] : 0.f;
      *reinterpret_cast<f32x4*>(&Ob[(size_t)i * T_ + jq]) = v;
    }
  }
}

extern "C" void kernel_launch(void* const* d_in, const int* in_sizes, int n_in,
                              void* d_out, int out_size, void* d_ws, size_t ws_size,
                              hipStream_t stream) {
  const float* pop = (const float*)d_in[0];
  float* out = (float*)d_out;
  dim3 blk(512);
  hipLaunchKernelGGL(fused_strip, dim3(16 * BH_), blk, 0, stream, pop, out);
}